// Round 4
// baseline (8833.134 us; speedup 1.0000x reference)
//
#include <hip/hip_runtime.h>
#include <math.h>
#include <stdint.h>

// Problem constants
constexpr int LL = 4096;   // seq len
constexpr int EE = 300;    // embedding dim
constexpr int HH = 256;    // per-direction hidden (H2)
constexpr int NGATE = 1024;// 4*HH
constexpr int TT = 16;     // tagset
constexpr float NEGV = -10000.0f;

// Workspace layout (byte offsets)
constexpr size_t OFF_SLOT = 0;                              // 8192 B (LLC slots)
constexpr size_t OFF_MIR  = 8192;                           // 8192 B (L2 mirror)
constexpr size_t OFF_X    = 16384;                          // L*E f32
constexpr size_t OFF_ZX   = OFF_X    + (size_t)LL*EE*4;     // 2*L*1024 f32
constexpr size_t OFF_HALL = OFF_ZX   + (size_t)2*LL*NGATE*4;// 2*L*256 f32
constexpr size_t OFF_FE   = OFF_HALL + (size_t)2*LL*HH*4;   // L*16 f32

// L2-path load: bypass L1 (sc0), served by this XCD's L2.
__device__ __forceinline__ unsigned long long l2_load_u64(const unsigned long long* p) {
  unsigned long long v;
  asm volatile("global_load_dwordx2 %0, %1, off sc0\n\t"
               "s_waitcnt vmcnt(0)"
               : "=v"(v) : "v"(p) : "memory");
  return v;
}

__device__ __forceinline__ float fsigmoid(float x) {
  return __builtin_amdgcn_rcpf(1.f + __expf(-x));
}
__device__ __forceinline__ float ftanh(float x) {
  return 1.f - 2.f * __builtin_amdgcn_rcpf(1.f + __expf(2.f * x));
}

// ---------------------------------------------------------------------------
// Kernel 1: embedding gather
// ---------------------------------------------------------------------------
__global__ void gather_x(const int* __restrict__ sent, const float* __restrict__ emb,
                         float* __restrict__ X) {
  const int i = blockIdx.x * blockDim.x + threadIdx.x;
  const int total = LL * (EE / 4);
  if (i >= total) return;
  const int row = i / (EE / 4), c4 = i % (EE / 4);
  const int v = sent[row];
  reinterpret_cast<float4*>(X)[(size_t)row * (EE / 4) + c4] =
      reinterpret_cast<const float4*>(emb + (size_t)v * EE)[c4];
}

// ---------------------------------------------------------------------------
// Kernel 2: input GEMM  Zx[dir][t][n] = X[t]·W_ih[n] + b[n]
// ---------------------------------------------------------------------------
__global__ __launch_bounds__(256) void input_gemm(
    const float* __restrict__ X, const float* __restrict__ w_f,
    const float* __restrict__ b_f, const float* __restrict__ w_b,
    const float* __restrict__ b_b, float* __restrict__ ZX) {
  const int dir = blockIdx.z;
  const float* __restrict__ W  = dir ? w_b : w_f;
  const float* __restrict__ Bv = dir ? b_b : b_f;
  float* __restrict__ Z = ZX + (size_t)dir * LL * NGATE;
  __shared__ float As[32][68];
  __shared__ float Bs[32][68];
  const int m0 = blockIdx.y * 64, n0 = blockIdx.x * 64;
  const int t = threadIdx.x;
  const int tx = t & 15, ty = t >> 4;
  float acc[4][4] = {};
  for (int k0 = 0; k0 < EE; k0 += 32) {
#pragma unroll
    for (int r = 0; r < 2; ++r) {
      const int idx = t + r * 256;
      const int row = idx >> 3;
      const int kk4 = (idx & 7) << 2;
      const int k = k0 + kk4;
      float4 va = make_float4(0.f, 0.f, 0.f, 0.f), vb = va;
      if (k < EE) {
        va = *reinterpret_cast<const float4*>(X + (size_t)(m0 + row) * EE + k);
        vb = *reinterpret_cast<const float4*>(W + (size_t)(n0 + row) * EE + k);
      }
      As[kk4 + 0][row] = va.x; As[kk4 + 1][row] = va.y;
      As[kk4 + 2][row] = va.z; As[kk4 + 3][row] = va.w;
      Bs[kk4 + 0][row] = vb.x; Bs[kk4 + 1][row] = vb.y;
      Bs[kk4 + 2][row] = vb.z; Bs[kk4 + 3][row] = vb.w;
    }
    __syncthreads();
    const int kmax = (EE - k0 < 32) ? (EE - k0) : 32;
    for (int k = 0; k < kmax; ++k) {
      const float4 av = *reinterpret_cast<const float4*>(&As[k][ty << 2]);
      const float4 bv = *reinterpret_cast<const float4*>(&Bs[k][tx << 2]);
      acc[0][0] += av.x * bv.x; acc[0][1] += av.x * bv.y; acc[0][2] += av.x * bv.z; acc[0][3] += av.x * bv.w;
      acc[1][0] += av.y * bv.x; acc[1][1] += av.y * bv.y; acc[1][2] += av.y * bv.z; acc[1][3] += av.y * bv.w;
      acc[2][0] += av.z * bv.x; acc[2][1] += av.z * bv.y; acc[2][2] += av.z * bv.z; acc[2][3] += av.z * bv.w;
      acc[3][0] += av.w * bv.x; acc[3][1] += av.w * bv.y; acc[3][2] += av.w * bv.z; acc[3][3] += av.w * bv.w;
    }
    __syncthreads();
  }
#pragma unroll
  for (int i = 0; i < 4; ++i)
#pragma unroll
    for (int j = 0; j < 4; ++j) {
      const int m = m0 + (ty << 2) + i, n = n0 + (tx << 2) + j;
      Z[(size_t)m * NGATE + n] = acc[i][j] + Bv[n];
    }
}

// ---------------------------------------------------------------------------
// Kernel 3: persistent bidirectional LSTM recurrence.
// Grid = 32 blocks; active only where (blockIdx&7) < 2 (XCD co-location
// heuristic; correctness does not depend on it).
// __launch_bounds__(512, 1): VGPR budget 512/thread so the 128 weight
// registers per thread STAY resident (R3 post-mortem: at default occupancy
// the compiler rematerialized the weight loads from L2 every step — the
// hidden ~2000 cyc/step tax). Inline-asm "+v" pins defeat rematerialization.
// h exchange: tagged u64 via XCD-local L2 mirror (plain stores + sc0 polls)
// with LLC agent-atomic fallback every 4th probe.
// ---------------------------------------------------------------------------
__global__ __launch_bounds__(512, 1) void recurrence(
    const float* __restrict__ whh_f, const float* __restrict__ whh_b,
    const float* __restrict__ h0, const float* __restrict__ c0,
    const float* __restrict__ ZX, float* __restrict__ HALL,
    unsigned long long* __restrict__ SLOT, unsigned long long* __restrict__ MIR) {
  const int lane7 = blockIdx.x & 7;
  if (lane7 >= 2) return;                       // dummy blocks (XCD placement)
  const int dir = lane7;
  const int g = blockIdx.x >> 3;
  const int t = threadIdx.x;
  const float* __restrict__ Whh = dir ? whh_b : whh_f;
  const float* __restrict__ Z = ZX + (size_t)dir * LL * NGATE;
  float* __restrict__ Hall = HALL + (size_t)dir * LL * HH;
  unsigned long long* __restrict__ slotD = SLOT + dir * 2 * HH; // [par][256]
  unsigned long long* __restrict__ mirD  = MIR  + dir * 2 * HH;
  const int rq = t & 63;
  const int kq = t >> 6;
  const int kbase = kq << 5;

  // Weights in VGPRs: thread (rq,kq) holds rows 4rq..4rq+3 (this WG's 64
  // units x 4 gates), k in [kq*32, kq*32+32). Pinned via asm value barrier.
  float w[4][32];
#pragma unroll
  for (int j = 0; j < 4; ++j) {
    const int lr = (rq << 2) + j;
    const int grow = ((lr >> 6) << 8) + (g << 6) + (lr & 63); // gate*256 + g*64 + u
    const float* wr = Whh + (size_t)grow * HH + kbase;
#pragma unroll
    for (int kk = 0; kk < 32; kk += 4) {
      const float4 v = *reinterpret_cast<const float4*>(wr + kk);
      w[j][kk] = v.x; w[j][kk + 1] = v.y; w[j][kk + 2] = v.z; w[j][kk + 3] = v.w;
      asm volatile("" : "+v"(w[j][kk]), "+v"(w[j][kk + 1]),
                        "+v"(w[j][kk + 2]), "+v"(w[j][kk + 3]));
    }
  }

  __shared__ float part[8][260];   // [kq][local gate row]
  __shared__ float hsh[2][256];    // [parity][h]

  float c_reg = 0.f;
  if (t < 64) {
    const int u = (g << 6) + t;
    c_reg = c0[dir * HH + u];
    const float h0v = h0[dir * HH + u];
    hsh[0][u] = h0v;
    const unsigned long long v0 = (unsigned long long)__float_as_uint(h0v); // tag 0
    __hip_atomic_store(&mirD[u],  v0, __ATOMIC_RELAXED, __HIP_MEMORY_SCOPE_WORKGROUP);
    __hip_atomic_store(&slotD[u], v0, __ATOMIC_RELAXED, __HIP_MEMORY_SCOPE_AGENT);
  }

  // prefetch Zx for step 0
  float zx0 = 0.f, zx1 = 0.f, zx2 = 0.f, zx3 = 0.f;
  if (t < 64) {
    const int trow0 = dir ? (LL - 1) : 0;
    const float* zp = Z + (size_t)trow0 * NGATE + (g << 6) + t;
    zx0 = zp[0]; zx1 = zp[HH]; zx2 = zp[2 * HH]; zx3 = zp[3 * HH];
  }

  for (int s = 0; s < LL; ++s) {
    const int par = s & 1;
    // prefetch next step's Zx
    float nzx0 = 0.f, nzx1 = 0.f, nzx2 = 0.f, nzx3 = 0.f;
    if (t < 64 && s + 1 < LL) {
      const int trow = dir ? (LL - 2 - s) : (s + 1);
      const float* zp = Z + (size_t)trow * NGATE + (g << 6) + t;
      nzx0 = zp[0]; nzx1 = zp[HH]; nzx2 = zp[2 * HH]; nzx3 = zp[3 * HH];
    }
    // poll foreign h (tag == s): 3 L2-mirror probes per LLC-slot probe
    if (t < 256 && (t >> 6) != g) {
      const unsigned long long* mp = &mirD[par * HH + t];
      const unsigned long long* ap = &slotD[par * HH + t];
      unsigned long long v;
      for (;;) {
        v = l2_load_u64(mp); if ((unsigned)(v >> 32) == (unsigned)s) break;
        v = l2_load_u64(mp); if ((unsigned)(v >> 32) == (unsigned)s) break;
        v = l2_load_u64(mp); if ((unsigned)(v >> 32) == (unsigned)s) break;
        v = __hip_atomic_load(ap, __ATOMIC_RELAXED, __HIP_MEMORY_SCOPE_AGENT);
        if ((unsigned)(v >> 32) == (unsigned)s) break;
      }
      hsh[par][t] = __uint_as_float((unsigned)v);
    }
    __syncthreads();

    // matvec: h slice from LDS
    const float* hp = &hsh[par][kbase];
    float hv[32];
#pragma unroll
    for (int kk = 0; kk < 32; kk += 4) {
      const float4 v = *reinterpret_cast<const float4*>(hp + kk);
      hv[kk] = v.x; hv[kk + 1] = v.y; hv[kk + 2] = v.z; hv[kk + 3] = v.w;
    }
    float a0 = 0.f, a1 = 0.f, a2 = 0.f, a3 = 0.f;
#pragma unroll
    for (int kk = 0; kk < 32; ++kk) {
      const float h = hv[kk];
      a0 += w[0][kk] * h; a1 += w[1][kk] * h; a2 += w[2][kk] * h; a3 += w[3][kk] * h;
    }
    *reinterpret_cast<float4*>(&part[kq][rq << 2]) = make_float4(a0, a1, a2, a3);
    __syncthreads();

    if (t < 64) {
      float z0 = zx0, z1 = zx1, z2 = zx2, z3 = zx3;
#pragma unroll
      for (int k2 = 0; k2 < 8; ++k2) {
        z0 += part[k2][t];
        z1 += part[k2][64 + t];
        z2 += part[k2][128 + t];
        z3 += part[k2][192 + t];
      }
      const float ig = fsigmoid(z0);
      const float fg = fsigmoid(z1);
      const float gg = ftanh(z2);
      const float og = fsigmoid(z3);
      c_reg = fg * c_reg + ig * gg;
      const float hval = og * ftanh(c_reg);
      const int u = (g << 6) + t;
      const unsigned long long v =
          ((unsigned long long)(unsigned)(s + 1) << 32) | (unsigned long long)__float_as_uint(hval);
      const int np = (s + 1) & 1;
      __hip_atomic_store(&mirD[np * HH + u],  v, __ATOMIC_RELAXED, __HIP_MEMORY_SCOPE_WORKGROUP);
      __hip_atomic_store(&slotD[np * HH + u], v, __ATOMIC_RELAXED, __HIP_MEMORY_SCOPE_AGENT);
      hsh[np][u] = hval;
      const int trow = dir ? (LL - 1 - s) : s;
      Hall[(size_t)trow * HH + u] = hval;
    }
    zx0 = nzx0; zx1 = nzx1; zx2 = nzx2; zx3 = nzx3;
  }
}

// ---------------------------------------------------------------------------
// Kernel 4: feats
// ---------------------------------------------------------------------------
__global__ __launch_bounds__(256) void feats_gemm(
    const float* __restrict__ HALL, const float* __restrict__ Wout,
    const float* __restrict__ bout, float* __restrict__ FE) {
  __shared__ float Wl[16][516];
  const int t = threadIdx.x;
  for (int i = t; i < 16 * 512; i += 256) Wl[i >> 9][i & 511] = Wout[i];
  __syncthreads();
  const int row = blockIdx.x * 16 + (t >> 4);
  const int j = t & 15;
  const float* hf = HALL + (size_t)row * HH;
  const float* hb = HALL + (size_t)LL * HH + (size_t)row * HH;
  float acc = bout[j];
  for (int k = 0; k < HH; k += 4) {
    const float4 a = *reinterpret_cast<const float4*>(hf + k);
    const float4 wa = *reinterpret_cast<const float4*>(&Wl[j][k]);
    acc += a.x * wa.x + a.y * wa.y + a.z * wa.z + a.w * wa.w;
    const float4 b2 = *reinterpret_cast<const float4*>(hb + k);
    const float4 wb = *reinterpret_cast<const float4*>(&Wl[j][256 + k]);
    acc += b2.x * wb.x + b2.y * wb.y + b2.z * wb.z + b2.w * wb.w;
  }
  FE[(size_t)row * TT + j] = acc;
}

// ---------------------------------------------------------------------------
// Kernel 5: Viterbi (unchanged)
// ---------------------------------------------------------------------------
template <int CTRL>
__device__ __forceinline__ int dpp_i(int v) {
  return __builtin_amdgcn_mov_dpp(v, CTRL, 0xF, 0xF, true);
}
template <int CTRL>
__device__ __forceinline__ float dpp_f(float v) {
  return __int_as_float(__builtin_amdgcn_mov_dpp(__float_as_int(v), CTRL, 0xF, 0xF, true));
}
__device__ __forceinline__ float bperm_f(int lane, float v) {
  return __int_as_float(__builtin_amdgcn_ds_bpermute(lane << 2, __float_as_int(v)));
}

__global__ __launch_bounds__(1024) void viterbi(
    const float* __restrict__ FE, const float* __restrict__ trans,
    float* __restrict__ out) {
  __shared__ unsigned char bp8[LL * TT];
  __shared__ unsigned char xc[64 * 16];
  __shared__ unsigned char entry[64];
  __shared__ int sbest;
  const int t = threadIdx.x;

  if (t < 64) {
    const int n = t >> 2, pg = t & 3;
    const float tr0 = trans[n * 16 + (pg << 2) + 0];
    const float tr1 = trans[n * 16 + (pg << 2) + 1];
    const float tr2 = trans[n * 16 + (pg << 2) + 2];
    const float tr3 = trans[n * 16 + (pg << 2) + 3];
    float fvp0 = ((pg << 2) + 0 == 14) ? 0.f : NEGV;
    float fvp1 = ((pg << 2) + 1 == 14) ? 0.f : NEGV;
    float fvp2 = ((pg << 2) + 2 == 14) ? 0.f : NEGV;
    float fvp3 = ((pg << 2) + 3 == 14) ? 0.f : NEGV;

    auto step = [&](int s, float feat) {
      float bv = fvp0 + tr0; int bi = (pg << 2);
      float c;
      c = fvp1 + tr1; if (c > bv) { bv = c; bi = (pg << 2) + 1; }
      c = fvp2 + tr2; if (c > bv) { bv = c; bi = (pg << 2) + 2; }
      c = fvp3 + tr3; if (c > bv) { bv = c; bi = (pg << 2) + 3; }
      float pv = dpp_f<0xB1>(bv); int pi = dpp_i<0xB1>(bi);
      if (pv > bv || (pv == bv && pi < bi)) { bv = pv; bi = pi; }
      pv = dpp_f<0x4E>(bv); pi = dpp_i<0x4E>(bi);
      if (pv > bv || (pv == bv && pi < bi)) { bv = pv; bi = pi; }
      if (pg == 0) bp8[(s << 4) + n] = (unsigned char)bi;
      const float fvn = bv + feat;
      fvp0 = bperm_f((pg << 4) + 0,  fvn);
      fvp1 = bperm_f((pg << 4) + 4,  fvn);
      fvp2 = bperm_f((pg << 4) + 8,  fvn);
      fvp3 = bperm_f((pg << 4) + 12, fvn);
    };

    float fb0 = FE[(0 << 4) + n], fb1 = FE[(1 << 4) + n];
    float fb2 = FE[(2 << 4) + n], fb3 = FE[(3 << 4) + n];
    for (int s = 0; s < LL; s += 4) {
      step(s + 0, fb0); fb0 = (s + 4 < LL) ? FE[((s + 4) << 4) + n] : 0.f;
      step(s + 1, fb1); fb1 = (s + 5 < LL) ? FE[((s + 5) << 4) + n] : 0.f;
      step(s + 2, fb2); fb2 = (s + 6 < LL) ? FE[((s + 6) << 4) + n] : 0.f;
      step(s + 3, fb3); fb3 = (s + 7 < LL) ? FE[((s + 7) << 4) + n] : 0.f;
    }

    const float tt0 = trans[240 + (pg << 2) + 0];
    const float tt1 = trans[240 + (pg << 2) + 1];
    const float tt2 = trans[240 + (pg << 2) + 2];
    const float tt3 = trans[240 + (pg << 2) + 3];
    float bv = fvp0 + tt0; int bi = (pg << 2);
    float c;
    c = fvp1 + tt1; if (c > bv) { bv = c; bi = (pg << 2) + 1; }
    c = fvp2 + tt2; if (c > bv) { bv = c; bi = (pg << 2) + 2; }
    c = fvp3 + tt3; if (c > bv) { bv = c; bi = (pg << 2) + 3; }
    float pv = dpp_f<0xB1>(bv); int pi = dpp_i<0xB1>(bi);
    if (pv > bv || (pv == bv && pi < bi)) { bv = pv; bi = pi; }
    pv = dpp_f<0x4E>(bv); pi = dpp_i<0x4E>(bi);
    if (pv > bv || (pv == bv && pi < bi)) { bv = pv; bi = pi; }
    if (t == 0) { out[0] = bv; sbest = bi; }
  }
  __syncthreads();

  {
    const int c = t >> 4, e = t & 15;
    int tag = e;
#pragma unroll 1
    for (int i = 63; i >= 0; --i) tag = bp8[(((c << 6) + i) << 4) + tag];
    xc[(c << 4) + e] = (unsigned char)tag;
  }
  __syncthreads();
  if (t == 0) {
    int carry = sbest;
#pragma unroll 1
    for (int c = 63; c >= 0; --c) {
      entry[c] = (unsigned char)carry;
      carry = xc[(c << 4) + carry];
    }
  }
  __syncthreads();
  if (t < 64) {
    const int c = t;
    int tag = entry[c];
#pragma unroll 1
    for (int i = 63; i >= 0; --i) {
      const int s = (c << 6) + i;
      out[1 + s] = (float)tag;
      tag = bp8[(s << 4) + tag];
    }
  }
}

// ---------------------------------------------------------------------------
extern "C" void kernel_launch(void* const* d_in, const int* in_sizes, int n_in,
                              void* d_out, int out_size, void* d_ws, size_t ws_size,
                              hipStream_t stream) {
  const int*   sent = (const int*)d_in[0];
  const float* emb  = (const float*)d_in[1];
  const float* wihf = (const float*)d_in[2];
  const float* whhf = (const float*)d_in[3];
  const float* bf   = (const float*)d_in[4];
  const float* wihb = (const float*)d_in[5];
  const float* whhb = (const float*)d_in[6];
  const float* bb   = (const float*)d_in[7];
  const float* wout = (const float*)d_in[8];
  const float* bout = (const float*)d_in[9];
  const float* trans= (const float*)d_in[10];
  const float* h0   = (const float*)d_in[11];
  const float* c0   = (const float*)d_in[12];
  float* out = (float*)d_out;
  char* ws = (char*)d_ws;

  unsigned long long* SLOT = (unsigned long long*)(ws + OFF_SLOT);
  unsigned long long* MIR  = (unsigned long long*)(ws + OFF_MIR);
  float* X    = (float*)(ws + OFF_X);
  float* ZX   = (float*)(ws + OFF_ZX);
  float* HALL = (float*)(ws + OFF_HALL);
  float* FE   = (float*)(ws + OFF_FE);

  // No memset needed: 0xAA poison never matches a valid step tag (0..4096).
  gather_x<<<(LL * (EE / 4) + 255) / 256, 256, 0, stream>>>(sent, emb, X);
  input_gemm<<<dim3(16, 64, 2), 256, 0, stream>>>(X, wihf, bf, wihb, bb, ZX);
  recurrence<<<32, 512, 0, stream>>>(whhf, whhb, h0, c0, ZX, HALL, SLOT, MIR);
  feats_gemm<<<LL / 16, 256, 0, stream>>>(HALL, wout, bout, FE);
  viterbi<<<1, 1024, 0, stream>>>(FE, trans, out);
}

// Round 6
// 7256.583 us; speedup vs baseline: 1.2173x; 1.2173x over previous
//
#include <hip/hip_runtime.h>
#include <math.h>
#include <stdint.h>

// Problem constants
constexpr int LL = 4096;   // seq len
constexpr int EE = 300;    // embedding dim
constexpr int HH = 256;    // per-direction hidden (H2)
constexpr int NGATE = 1024;// 4*HH
constexpr int TT = 16;     // tagset
constexpr float NEGV = -10000.0f;

typedef _Float16 v2h __attribute__((ext_vector_type(2)));

// Workspace layout (byte offsets)
constexpr size_t OFF_SLOT = 0;                              // 8192 B (LLC slots)
constexpr size_t OFF_MIR  = 8192;                           // 8192 B (L2 mirror)
constexpr size_t OFF_X    = 16384;                          // L*E f32
constexpr size_t OFF_ZX   = OFF_X    + (size_t)LL*EE*4;     // 2*L*1024 f32
constexpr size_t OFF_HALL = OFF_ZX   + (size_t)2*LL*NGATE*4;// 2*L*256 f32
constexpr size_t OFF_FE   = OFF_HALL + (size_t)2*LL*HH*4;   // L*16 f32

// Pack two f32 to f16x2 (RTZ), bit-cast to the _Float16 vector type fdot2 wants.
__device__ __forceinline__ v2h pack_h2(float x, float y) {
  return __builtin_bit_cast(v2h, __builtin_amdgcn_cvt_pkrtz(x, y));
}

// L2-path load: bypass L1 (sc0), served by this XCD's L2.
__device__ __forceinline__ unsigned long long l2_load_u64(const unsigned long long* p) {
  unsigned long long v;
  asm volatile("global_load_dwordx2 %0, %1, off sc0\n\t"
               "s_waitcnt vmcnt(0)"
               : "=v"(v) : "v"(p) : "memory");
  return v;
}
// Dual probe: mirror (L2) + slot (LLC, sc0 sc1) issued concurrently, one wait.
__device__ __forceinline__ void dual_probe(const unsigned long long* mp,
                                           const unsigned long long* ap,
                                           unsigned long long& vm,
                                           unsigned long long& va) {
  asm volatile("global_load_dwordx2 %0, %2, off sc0\n\t"
               "global_load_dwordx2 %1, %3, off sc0 sc1\n\t"
               "s_waitcnt vmcnt(0)"
               : "=v"(vm), "=v"(va) : "v"(mp), "v"(ap) : "memory");
}

__device__ __forceinline__ float fsigmoid(float x) {
  return __builtin_amdgcn_rcpf(1.f + __expf(-x));
}
__device__ __forceinline__ float ftanh(float x) {
  return 1.f - 2.f * __builtin_amdgcn_rcpf(1.f + __expf(2.f * x));
}

// ---------------------------------------------------------------------------
// Kernel 1: embedding gather
// ---------------------------------------------------------------------------
__global__ void gather_x(const int* __restrict__ sent, const float* __restrict__ emb,
                         float* __restrict__ X) {
  const int i = blockIdx.x * blockDim.x + threadIdx.x;
  const int total = LL * (EE / 4);
  if (i >= total) return;
  const int row = i / (EE / 4), c4 = i % (EE / 4);
  const int v = sent[row];
  reinterpret_cast<float4*>(X)[(size_t)row * (EE / 4) + c4] =
      reinterpret_cast<const float4*>(emb + (size_t)v * EE)[c4];
}

// ---------------------------------------------------------------------------
// Kernel 2: input GEMM  Zx[dir][t][n] = X[t]·W_ih[n] + b[n]
// ---------------------------------------------------------------------------
__global__ __launch_bounds__(256) void input_gemm(
    const float* __restrict__ X, const float* __restrict__ w_f,
    const float* __restrict__ b_f, const float* __restrict__ w_b,
    const float* __restrict__ b_b, float* __restrict__ ZX) {
  const int dir = blockIdx.z;
  const float* __restrict__ W  = dir ? w_b : w_f;
  const float* __restrict__ Bv = dir ? b_b : b_f;
  float* __restrict__ Z = ZX + (size_t)dir * LL * NGATE;
  __shared__ float As[32][68];
  __shared__ float Bs[32][68];
  const int m0 = blockIdx.y * 64, n0 = blockIdx.x * 64;
  const int t = threadIdx.x;
  const int tx = t & 15, ty = t >> 4;
  float acc[4][4] = {};
  for (int k0 = 0; k0 < EE; k0 += 32) {
#pragma unroll
    for (int r = 0; r < 2; ++r) {
      const int idx = t + r * 256;
      const int row = idx >> 3;
      const int kk4 = (idx & 7) << 2;
      const int k = k0 + kk4;
      float4 va = make_float4(0.f, 0.f, 0.f, 0.f), vb = va;
      if (k < EE) {
        va = *reinterpret_cast<const float4*>(X + (size_t)(m0 + row) * EE + k);
        vb = *reinterpret_cast<const float4*>(W + (size_t)(n0 + row) * EE + k);
      }
      As[kk4 + 0][row] = va.x; As[kk4 + 1][row] = va.y;
      As[kk4 + 2][row] = va.z; As[kk4 + 3][row] = va.w;
      Bs[kk4 + 0][row] = vb.x; Bs[kk4 + 1][row] = vb.y;
      Bs[kk4 + 2][row] = vb.z; Bs[kk4 + 3][row] = vb.w;
    }
    __syncthreads();
    const int kmax = (EE - k0 < 32) ? (EE - k0) : 32;
    for (int k = 0; k < kmax; ++k) {
      const float4 av = *reinterpret_cast<const float4*>(&As[k][ty << 2]);
      const float4 bv = *reinterpret_cast<const float4*>(&Bs[k][tx << 2]);
      acc[0][0] += av.x * bv.x; acc[0][1] += av.x * bv.y; acc[0][2] += av.x * bv.z; acc[0][3] += av.x * bv.w;
      acc[1][0] += av.y * bv.x; acc[1][1] += av.y * bv.y; acc[1][2] += av.y * bv.z; acc[1][3] += av.y * bv.w;
      acc[2][0] += av.z * bv.x; acc[2][1] += av.z * bv.y; acc[2][2] += av.z * bv.z; acc[2][3] += av.z * bv.w;
      acc[3][0] += av.w * bv.x; acc[3][1] += av.w * bv.y; acc[3][2] += av.w * bv.z; acc[3][3] += av.w * bv.w;
    }
    __syncthreads();
  }
#pragma unroll
  for (int i = 0; i < 4; ++i)
#pragma unroll
    for (int j = 0; j < 4; ++j) {
      const int m = m0 + (ty << 2) + i, n = n0 + (tx << 2) + j;
      Z[(size_t)m * NGATE + n] = acc[i][j] + Bv[n];
    }
}

// ---------------------------------------------------------------------------
// Kernel 3: persistent bidirectional LSTM recurrence.
// Grid = 32 blocks; active only where (blockIdx&7) < 2 (XCD co-location
// heuristic; correctness never depends on it — LLC slots are the fallback).
// R4 post-mortem: at 128 f32 weight regs/thread the allocator ALWAYS spilled
// (VGPR_Count 84) and restreamed 256KB/WG/step — the dominant cost. Fix:
//   * f16-packed weights (64 VGPRs/thread) + v_dot2_f32_f16 math
//   * amdgpu_waves_per_eu(2,2): occupancy pinned, no incentive to spill
// ---------------------------------------------------------------------------
__global__ __launch_bounds__(512) __attribute__((amdgpu_waves_per_eu(2, 2)))
void recurrence(
    const float* __restrict__ whh_f, const float* __restrict__ whh_b,
    const float* __restrict__ h0, const float* __restrict__ c0,
    const float* __restrict__ ZX, float* __restrict__ HALL,
    unsigned long long* __restrict__ SLOT, unsigned long long* __restrict__ MIR) {
  const int lane7 = blockIdx.x & 7;
  if (lane7 >= 2) return;                       // dummy blocks (XCD placement)
  const int dir = lane7;
  const int g = blockIdx.x >> 3;
  const int t = threadIdx.x;
  const float* __restrict__ Whh = dir ? whh_b : whh_f;
  const float* __restrict__ Z = ZX + (size_t)dir * LL * NGATE;
  float* __restrict__ Hall = HALL + (size_t)dir * LL * HH;
  unsigned long long* __restrict__ slotD = SLOT + dir * 2 * HH; // [par][256]
  unsigned long long* __restrict__ mirD  = MIR  + dir * 2 * HH;
  const int rq = t & 63;
  const int kq = t >> 6;
  const int kbase = kq << 5;

  // Weights in VGPRs as f16 pairs along k: thread (rq,kq) holds rows
  // 4rq..4rq+3 (this WG's 64 units x 4 gates), k in [kq*32, kq*32+32)
  // -> w2[4][16] = 64 VGPRs. Pinned with value barriers.
  v2h w2[4][16];
#pragma unroll
  for (int j = 0; j < 4; ++j) {
    const int lr = (rq << 2) + j;
    const int grow = ((lr >> 6) << 8) + (g << 6) + (lr & 63); // gate*256 + g*64 + u
    const float* wr = Whh + (size_t)grow * HH + kbase;
#pragma unroll
    for (int p = 0; p < 16; ++p) {
      const float2 v = *reinterpret_cast<const float2*>(wr + 2 * p);
      w2[j][p] = pack_h2(v.x, v.y);
      asm volatile("" : "+v"(w2[j][p]));
    }
  }

  __shared__ float part[8][260];   // [kq][local gate row]
  __shared__ float hsh[2][256];    // [parity][h]

  float c_reg = 0.f;
  if (t < 64) {
    const int u = (g << 6) + t;
    c_reg = c0[dir * HH + u];
    const float h0v = h0[dir * HH + u];
    hsh[0][u] = h0v;
    const unsigned long long v0 = (unsigned long long)__float_as_uint(h0v); // tag 0
    __hip_atomic_store(&mirD[u],  v0, __ATOMIC_RELAXED, __HIP_MEMORY_SCOPE_WORKGROUP);
    __hip_atomic_store(&slotD[u], v0, __ATOMIC_RELAXED, __HIP_MEMORY_SCOPE_AGENT);
  }

  // prefetch Zx for step 0
  float zx0 = 0.f, zx1 = 0.f, zx2 = 0.f, zx3 = 0.f;
  if (t < 64) {
    const int trow0 = dir ? (LL - 1) : 0;
    const float* zp = Z + (size_t)trow0 * NGATE + (g << 6) + t;
    zx0 = zp[0]; zx1 = zp[HH]; zx2 = zp[2 * HH]; zx3 = zp[3 * HH];
  }

  for (int s = 0; s < LL; ++s) {
    const int par = s & 1;
    // prefetch next step's Zx
    float nzx0 = 0.f, nzx1 = 0.f, nzx2 = 0.f, nzx3 = 0.f;
    if (t < 64 && s + 1 < LL) {
      const int trow = dir ? (LL - 2 - s) : (s + 1);
      const float* zp = Z + (size_t)trow * NGATE + (g << 6) + t;
      nzx0 = zp[0]; nzx1 = zp[HH]; nzx2 = zp[2 * HH]; nzx3 = zp[3 * HH];
    }
    // poll foreign h (tag == s): cheap mirror probe, then mirror+LLC dual probe
    if (t < 256 && (t >> 6) != g) {
      const unsigned long long* mp = &mirD[par * HH + t];
      const unsigned long long* ap = &slotD[par * HH + t];
      unsigned long long v;
      for (;;) {
        v = l2_load_u64(mp); if ((unsigned)(v >> 32) == (unsigned)s) break;
        unsigned long long vm, va;
        dual_probe(mp, ap, vm, va);
        if ((unsigned)(vm >> 32) == (unsigned)s) { v = vm; break; }
        if ((unsigned)(va >> 32) == (unsigned)s) { v = va; break; }
      }
      hsh[par][t] = __uint_as_float((unsigned)v);
    }
    __syncthreads();

    // matvec: h slice from LDS, f16 pack, dot2 accumulate in f32
    const float* hp = &hsh[par][kbase];
    v2h hh[16];
#pragma unroll
    for (int p = 0; p < 16; ++p) {
      const float2 v = *reinterpret_cast<const float2*>(hp + 2 * p);
      hh[p] = pack_h2(v.x, v.y);
    }
    float a0 = 0.f, a1 = 0.f, a2 = 0.f, a3 = 0.f;
#pragma unroll
    for (int p = 0; p < 16; ++p) {
      a0 = __builtin_amdgcn_fdot2(w2[0][p], hh[p], a0, false);
      a1 = __builtin_amdgcn_fdot2(w2[1][p], hh[p], a1, false);
      a2 = __builtin_amdgcn_fdot2(w2[2][p], hh[p], a2, false);
      a3 = __builtin_amdgcn_fdot2(w2[3][p], hh[p], a3, false);
    }
    *reinterpret_cast<float4*>(&part[kq][rq << 2]) = make_float4(a0, a1, a2, a3);
    __syncthreads();

    if (t < 64) {
      float z0 = zx0, z1 = zx1, z2 = zx2, z3 = zx3;
#pragma unroll
      for (int k2 = 0; k2 < 8; ++k2) {
        z0 += part[k2][t];
        z1 += part[k2][64 + t];
        z2 += part[k2][128 + t];
        z3 += part[k2][192 + t];
      }
      const float ig = fsigmoid(z0);
      const float fg = fsigmoid(z1);
      const float gg = ftanh(z2);
      const float og = fsigmoid(z3);
      c_reg = fg * c_reg + ig * gg;
      const float hval = og * ftanh(c_reg);
      const int u = (g << 6) + t;
      const unsigned long long v =
          ((unsigned long long)(unsigned)(s + 1) << 32) | (unsigned long long)__float_as_uint(hval);
      const int np = (s + 1) & 1;
      __hip_atomic_store(&mirD[np * HH + u],  v, __ATOMIC_RELAXED, __HIP_MEMORY_SCOPE_WORKGROUP);
      __hip_atomic_store(&slotD[np * HH + u], v, __ATOMIC_RELAXED, __HIP_MEMORY_SCOPE_AGENT);
      hsh[np][u] = hval;
      const int trow = dir ? (LL - 1 - s) : s;
      Hall[(size_t)trow * HH + u] = hval;
    }
    zx0 = nzx0; zx1 = nzx1; zx2 = nzx2; zx3 = nzx3;
  }
}

// ---------------------------------------------------------------------------
// Kernel 4: feats
// ---------------------------------------------------------------------------
__global__ __launch_bounds__(256) void feats_gemm(
    const float* __restrict__ HALL, const float* __restrict__ Wout,
    const float* __restrict__ bout, float* __restrict__ FE) {
  __shared__ float Wl[16][516];
  const int t = threadIdx.x;
  for (int i = t; i < 16 * 512; i += 256) Wl[i >> 9][i & 511] = Wout[i];
  __syncthreads();
  const int row = blockIdx.x * 16 + (t >> 4);
  const int j = t & 15;
  const float* hf = HALL + (size_t)row * HH;
  const float* hb = HALL + (size_t)LL * HH + (size_t)row * HH;
  float acc = bout[j];
  for (int k = 0; k < HH; k += 4) {
    const float4 a = *reinterpret_cast<const float4*>(hf + k);
    const float4 wa = *reinterpret_cast<const float4*>(&Wl[j][k]);
    acc += a.x * wa.x + a.y * wa.y + a.z * wa.z + a.w * wa.w;
    const float4 b2 = *reinterpret_cast<const float4*>(hb + k);
    const float4 wb = *reinterpret_cast<const float4*>(&Wl[j][256 + k]);
    acc += b2.x * wb.x + b2.y * wb.y + b2.z * wb.z + b2.w * wb.w;
  }
  FE[(size_t)row * TT + j] = acc;
}

// ---------------------------------------------------------------------------
// Kernel 5: Viterbi (unchanged)
// ---------------------------------------------------------------------------
template <int CTRL>
__device__ __forceinline__ int dpp_i(int v) {
  return __builtin_amdgcn_mov_dpp(v, CTRL, 0xF, 0xF, true);
}
template <int CTRL>
__device__ __forceinline__ float dpp_f(float v) {
  return __int_as_float(__builtin_amdgcn_mov_dpp(__float_as_int(v), CTRL, 0xF, 0xF, true));
}
__device__ __forceinline__ float bperm_f(int lane, float v) {
  return __int_as_float(__builtin_amdgcn_ds_bpermute(lane << 2, __float_as_int(v)));
}

__global__ __launch_bounds__(1024) void viterbi(
    const float* __restrict__ FE, const float* __restrict__ trans,
    float* __restrict__ out) {
  __shared__ unsigned char bp8[LL * TT];
  __shared__ unsigned char xc[64 * 16];
  __shared__ unsigned char entry[64];
  __shared__ int sbest;
  const int t = threadIdx.x;

  if (t < 64) {
    const int n = t >> 2, pg = t & 3;
    const float tr0 = trans[n * 16 + (pg << 2) + 0];
    const float tr1 = trans[n * 16 + (pg << 2) + 1];
    const float tr2 = trans[n * 16 + (pg << 2) + 2];
    const float tr3 = trans[n * 16 + (pg << 2) + 3];
    float fvp0 = ((pg << 2) + 0 == 14) ? 0.f : NEGV;
    float fvp1 = ((pg << 2) + 1 == 14) ? 0.f : NEGV;
    float fvp2 = ((pg << 2) + 2 == 14) ? 0.f : NEGV;
    float fvp3 = ((pg << 2) + 3 == 14) ? 0.f : NEGV;

    auto step = [&](int s, float feat) {
      float bv = fvp0 + tr0; int bi = (pg << 2);
      float c;
      c = fvp1 + tr1; if (c > bv) { bv = c; bi = (pg << 2) + 1; }
      c = fvp2 + tr2; if (c > bv) { bv = c; bi = (pg << 2) + 2; }
      c = fvp3 + tr3; if (c > bv) { bv = c; bi = (pg << 2) + 3; }
      float pv = dpp_f<0xB1>(bv); int pi = dpp_i<0xB1>(bi);
      if (pv > bv || (pv == bv && pi < bi)) { bv = pv; bi = pi; }
      pv = dpp_f<0x4E>(bv); pi = dpp_i<0x4E>(bi);
      if (pv > bv || (pv == bv && pi < bi)) { bv = pv; bi = pi; }
      if (pg == 0) bp8[(s << 4) + n] = (unsigned char)bi;
      const float fvn = bv + feat;
      fvp0 = bperm_f((pg << 4) + 0,  fvn);
      fvp1 = bperm_f((pg << 4) + 4,  fvn);
      fvp2 = bperm_f((pg << 4) + 8,  fvn);
      fvp3 = bperm_f((pg << 4) + 12, fvn);
    };

    float fb0 = FE[(0 << 4) + n], fb1 = FE[(1 << 4) + n];
    float fb2 = FE[(2 << 4) + n], fb3 = FE[(3 << 4) + n];
    for (int s = 0; s < LL; s += 4) {
      step(s + 0, fb0); fb0 = (s + 4 < LL) ? FE[((s + 4) << 4) + n] : 0.f;
      step(s + 1, fb1); fb1 = (s + 5 < LL) ? FE[((s + 5) << 4) + n] : 0.f;
      step(s + 2, fb2); fb2 = (s + 6 < LL) ? FE[((s + 6) << 4) + n] : 0.f;
      step(s + 3, fb3); fb3 = (s + 7 < LL) ? FE[((s + 7) << 4) + n] : 0.f;
    }

    const float tt0 = trans[240 + (pg << 2) + 0];
    const float tt1 = trans[240 + (pg << 2) + 1];
    const float tt2 = trans[240 + (pg << 2) + 2];
    const float tt3 = trans[240 + (pg << 2) + 3];
    float bv = fvp0 + tt0; int bi = (pg << 2);
    float c;
    c = fvp1 + tt1; if (c > bv) { bv = c; bi = (pg << 2) + 1; }
    c = fvp2 + tt2; if (c > bv) { bv = c; bi = (pg << 2) + 2; }
    c = fvp3 + tt3; if (c > bv) { bv = c; bi = (pg << 2) + 3; }
    float pv = dpp_f<0xB1>(bv); int pi = dpp_i<0xB1>(bi);
    if (pv > bv || (pv == bv && pi < bi)) { bv = pv; bi = pi; }
    pv = dpp_f<0x4E>(bv); pi = dpp_i<0x4E>(bi);
    if (pv > bv || (pv == bv && pi < bi)) { bv = pv; bi = pi; }
    if (t == 0) { out[0] = bv; sbest = bi; }
  }
  __syncthreads();

  {
    const int c = t >> 4, e = t & 15;
    int tag = e;
#pragma unroll 1
    for (int i = 63; i >= 0; --i) tag = bp8[(((c << 6) + i) << 4) + tag];
    xc[(c << 4) + e] = (unsigned char)tag;
  }
  __syncthreads();
  if (t == 0) {
    int carry = sbest;
#pragma unroll 1
    for (int c = 63; c >= 0; --c) {
      entry[c] = (unsigned char)carry;
      carry = xc[(c << 4) + carry];
    }
  }
  __syncthreads();
  if (t < 64) {
    const int c = t;
    int tag = entry[c];
#pragma unroll 1
    for (int i = 63; i >= 0; --i) {
      const int s = (c << 6) + i;
      out[1 + s] = (float)tag;
      tag = bp8[(s << 4) + tag];
    }
  }
}

// ---------------------------------------------------------------------------
extern "C" void kernel_launch(void* const* d_in, const int* in_sizes, int n_in,
                              void* d_out, int out_size, void* d_ws, size_t ws_size,
                              hipStream_t stream) {
  const int*   sent = (const int*)d_in[0];
  const float* emb  = (const float*)d_in[1];
  const float* wihf = (const float*)d_in[2];
  const float* whhf = (const float*)d_in[3];
  const float* bf   = (const float*)d_in[4];
  const float* wihb = (const float*)d_in[5];
  const float* whhb = (const float*)d_in[6];
  const float* bb   = (const float*)d_in[7];
  const float* wout = (const float*)d_in[8];
  const float* bout = (const float*)d_in[9];
  const float* trans= (const float*)d_in[10];
  const float* h0   = (const float*)d_in[11];
  const float* c0   = (const float*)d_in[12];
  float* out = (float*)d_out;
  char* ws = (char*)d_ws;

  unsigned long long* SLOT = (unsigned long long*)(ws + OFF_SLOT);
  unsigned long long* MIR  = (unsigned long long*)(ws + OFF_MIR);
  float* X    = (float*)(ws + OFF_X);
  float* ZX   = (float*)(ws + OFF_ZX);
  float* HALL = (float*)(ws + OFF_HALL);
  float* FE   = (float*)(ws + OFF_FE);

  // No memset needed: 0xAA poison never matches a valid step tag (0..4096).
  gather_x<<<(LL * (EE / 4) + 255) / 256, 256, 0, stream>>>(sent, emb, X);
  input_gemm<<<dim3(16, 64, 2), 256, 0, stream>>>(X, wihf, bf, wihb, bb, ZX);
  recurrence<<<32, 512, 0, stream>>>(whhf, whhb, h0, c0, ZX, HALL, SLOT, MIR);
  feats_gemm<<<LL / 16, 256, 0, stream>>>(HALL, wout, bout, FE);
  viterbi<<<1, 1024, 0, stream>>>(FE, trans, out);
}